// Round 14
// baseline (138.630 us; speedup 1.0000x reference)
//
#include <hip/hip_runtime.h>
#include <hip/hip_bf16.h>
#include <stdint.h>

#define N_TOTAL 8192
#define HALF_N  4096
#define DIM     512
#define INV_TAU (1.0f/0.07f)
// exp2 fold: e = exp2(sim * INV_TAU * log2e); SCALE^2 = INV_TAU*log2e
#define EXP2_SCALE  4.5398160046388386f     /* sqrt(20.60992915555662) */
#define SIM_FROM_VE 0.0485203026391962f     /* 0.07 * ln2 */

typedef __attribute__((ext_vector_type(4))) int   i32x4;

#define AS1 __attribute__((address_space(1)))
#define AS3 __attribute__((address_space(3)))

__device__ __forceinline__ uint32_t umax32(uint32_t a, uint32_t b) { return a > b ? a : b; }
__device__ __forceinline__ uint32_t umin32(uint32_t a, uint32_t b) { return a < b ? a : b; }

__device__ __forceinline__ float decode_key(uint32_t key)
{
    ushort h = (key & 0x8000u) ? (ushort)(key ^ 0x8000u) : (ushort)(key ^ 0xFFFFu);
    return (float)(*(_Float16*)&h);
}

// ------- Kernel 0: normalize -> int8 quantize; inv_e = EXP2_SCALE/|q|;
//         zero rowsum and out ------------------------------------------
__global__ __launch_bounds__(256) void norm_kernel(const float* __restrict__ z1,
                                                   const float* __restrict__ z2,
                                                   char* __restrict__ zq,
                                                   float* __restrict__ inv_e,
                                                   float* __restrict__ rowsum,
                                                   float* __restrict__ out)
{
    if (threadIdx.x < 4) rowsum[blockIdx.x * 4 + threadIdx.x] = 0.f;
    if (blockIdx.x == 0 && threadIdx.x == 0) out[0] = 0.f;

    int row  = blockIdx.x * 4 + (threadIdx.x >> 6);
    int lane = threadIdx.x & 63;
    const float* src = (row < HALF_N) ? (z1 + (size_t)row * DIM)
                                      : (z2 + (size_t)(row - HALF_N) * DIM);
    const float4* p = (const float4*)src;
    float4 a = p[lane * 2];
    float4 b = p[lane * 2 + 1];
    float ss = a.x*a.x + a.y*a.y + a.z*a.z + a.w*a.w
             + b.x*b.x + b.y*b.y + b.z*b.z + b.w*b.w;
#pragma unroll
    for (int o = 1; o < 64; o <<= 1) ss += __shfl_xor(ss, o);
    float sc = 127.0f / fmaxf(sqrtf(ss), 1e-12f);

    float v[8] = {a.x*sc, a.y*sc, a.z*sc, a.w*sc, b.x*sc, b.y*sc, b.z*sc, b.w*sc};
    char c8[8];
    int qq = 0;
#pragma unroll
    for (int j = 0; j < 8; j++) {
        int qi = (int)rintf(v[j]);
        qq += qi * qi;
        c8[j] = (char)qi;
    }
#pragma unroll
    for (int o = 1; o < 64; o <<= 1) qq += __shfl_xor(qq, o);
    if (lane == 0) inv_e[row] = EXP2_SCALE / sqrtf(fmaxf((float)qq, 1.0f));

    *(uint2*)(zq + (size_t)row * DIM + lane * 8) = *(const uint2*)c8;
}

// ------- Kernel 1: upper-triangle 128x128 int8 MFMA GEMM (R12 core) ----
// LDS staging restored (R13 proved it's the coalescing device: direct
// per-lane loads = 16 cachelines/instr). Epilogue: loop-carried chains
// split 2-way (cs/s1/s2 a|b halves), exp2-folded scale, launch_bounds
// (256,5) for occupancy headroom (LDS caps at exactly 5 blocks/CU).
__global__ __launch_bounds__(256, 5) void gemm_kernel(const char* __restrict__ zq,
                                                      const float* __restrict__ inv_e,
                                                      float* __restrict__ rowsum,
                                                      uint2* __restrict__ partial,
                                                      float* __restrict__ pos_sim)
{
    // XCD-aware swizzle: 2080 = 8 * 260, bijective
    int orig = blockIdx.x;
    int bid  = (orig & 7) * 260 + (orig >> 3);

    // triangular decode: bid -> (by, bx), bx >= by
    int by = (int)(64.5f - sqrtf(4160.25f - 2.0f * (float)bid));
    int off = 64 * by - (by * (by - 1)) / 2;
    if (off > bid) { --by; off = 64 * by - (by * (by - 1)) / 2; }
    else {
        int offn = 64 * (by + 1) - ((by + 1) * by) / 2;
        if (offn <= bid) { ++by; off = offn; }
    }
    int bx = by + (bid - off);

    const int brow = by * 128;
    const int bcol = bx * 128;

    __shared__ char As[2][128 * 64];   // 8 KB per buffer
    __shared__ char Bs[2][128 * 64];   // 32 KB total

    const int t    = threadIdx.x;
    const int w    = t >> 6;
    const int lane = t & 63;
    const int wr   = w >> 1, wc = w & 1;       // 2x2 waves of 64x64

    i32x4 acc[4][4] = {};

    const int c0 = t, c1 = 256 + t;
    const int r0 = c0 >> 2, r1 = c1 >> 2;
    const int q0 = (c0 & 3) ^ ((r0 >> 1) & 3);
    const int q1 = (c1 & 3) ^ ((r1 >> 1) & 3);
    const size_t gaA0 = (size_t)(brow + r0) * DIM + q0 * 16;
    const size_t gaA1 = (size_t)(brow + r1) * DIM + q1 * 16;
    const size_t gaB0 = (size_t)(bcol + r0) * DIM + q0 * 16;
    const size_t gaB1 = (size_t)(bcol + r1) * DIM + q1 * 16;
    const int l0 = (w * 64) * 16;
    const int l1 = (256 + w * 64) * 16;

#define STAGE(buf, ko) do {                                                        \
    __builtin_amdgcn_global_load_lds((const AS1 uint32_t*)(zq + gaA0 + (ko)),      \
        (AS3 uint32_t*)((char*)As[buf] + l0), 16, 0, 0);                           \
    __builtin_amdgcn_global_load_lds((const AS1 uint32_t*)(zq + gaA1 + (ko)),      \
        (AS3 uint32_t*)((char*)As[buf] + l1), 16, 0, 0);                           \
    __builtin_amdgcn_global_load_lds((const AS1 uint32_t*)(zq + gaB0 + (ko)),      \
        (AS3 uint32_t*)((char*)Bs[buf] + l0), 16, 0, 0);                           \
    __builtin_amdgcn_global_load_lds((const AS1 uint32_t*)(zq + gaB1 + (ko)),      \
        (AS3 uint32_t*)((char*)Bs[buf] + l1), 16, 0, 0);                           \
} while (0)

    STAGE(0, 0);
    __syncthreads();

    int cur = 0;
    for (int kt = 0; kt < DIM / 64; ++kt) {
        if (kt + 1 < DIM / 64) STAGE(cur ^ 1, (kt + 1) * 64);

        i32x4 av[4], bv[4];
#pragma unroll
        for (int m = 0; m < 4; m++) {
            int ro = wr * 64 + m * 16 + (lane & 15);
            int s  = (lane >> 4) ^ ((ro >> 1) & 3);
            av[m] = *(const i32x4*)(As[cur] + ro * 64 + s * 16);
        }
#pragma unroll
        for (int n = 0; n < 4; n++) {
            int ro = wc * 64 + n * 16 + (lane & 15);
            int s  = (lane >> 4) ^ ((ro >> 1) & 3);
            bv[n] = *(const i32x4*)(Bs[cur] + ro * 64 + s * 16);
        }
#pragma unroll
        for (int m = 0; m < 4; m++)
#pragma unroll
            for (int n = 0; n < 4; n++)
                acc[m][n] = __builtin_amdgcn_mfma_i32_16x16x64_i8(av[m], bv[n], acc[m][n], 0, 0, 0);

        __syncthreads();
        cur ^= 1;
    }
#undef STAGE

    const bool is_cross = (brow < HALF_N) && (bcol >= HALF_N);
    const bool off_diag = (bx != by);

    float invc[4];
#pragma unroll
    for (int n = 0; n < 4; n++)
        invc[n] = inv_e[bcol + wc * 64 + n * 16 + (lane & 15)];

    // 2-way split accumulators (halve the loop-carried dep chains)
    float    cs0[4] = {0,0,0,0}, cs1[4] = {0,0,0,0};
    uint32_t s1a[4] = {0,0,0,0}, s2a[4] = {0,0,0,0};
    uint32_t s1b[4] = {0,0,0,0}, s2b[4] = {0,0,0,0};

    // ---- single fused epilogue pass ----
#pragma unroll
    for (int m = 0; m < 4; m++) {
#pragma unroll
        for (int r = 0; r < 4; r++) {
            int grow = brow + wr * 64 + m * 16 + ((lane >> 4) << 2) + r;
            float invr = inv_e[grow];
            float rs = 0.f;
            uint32_t t1 = 0u, t2 = 0u;
#pragma unroll
            for (int n = 0; n < 4; n++) {
                int gcol = bcol + wc * 64 + n * 16 + (lane & 15);
                float ve = (float)acc[m][n][r] * (invr * invc[n]);   // sim*INV_TAU*log2e
                float e  = (grow == gcol) ? 0.f : __builtin_exp2f(ve);
                rs += e;
                if (m < 2) cs0[n] += e; else cs1[n] += e;
                if (is_cross) {
                    float v = ve * SIM_FROM_VE;                      // raw sim
                    int cidx = gcol - HALF_N;
                    ushort h;
                    *(_Float16*)&h = (_Float16)v;
                    uint32_t key = ((uint32_t)(ushort)(h ^ (ushort)((ushort)((short)h >> 15) | 0x8000))) << 16;
                    uint32_t xr = key | (uint32_t)(4095 - cidx);
                    uint32_t mn = umin32(t1, xr);
                    t1 = umax32(t1, xr);
                    t2 = umax32(t2, mn);
                    uint32_t xc = key | (uint32_t)(4095 - grow);
                    if (m < 2) {
                        mn = umin32(s1a[n], xc); s1a[n] = umax32(s1a[n], xc); s2a[n] = umax32(s2a[n], mn);
                    } else {
                        mn = umin32(s1b[n], xc); s1b[n] = umax32(s1b[n], xc); s2b[n] = umax32(s2b[n], mn);
                    }
                    if (cidx == grow) { pos_sim[grow] = v; pos_sim[gcol] = v; }
                }
            }
            rs += __shfl_xor(rs, 1);
            rs += __shfl_xor(rs, 2);
            rs += __shfl_xor(rs, 4);
            rs += __shfl_xor(rs, 8);
            if ((lane & 15) == 0) atomicAdd(&rowsum[grow], rs);

            if (is_cross) {
#pragma unroll
                for (int o = 1; o < 16; o <<= 1) {
                    uint32_t o1 = __shfl_xor(t1, o);
                    uint32_t o2 = __shfl_xor(t2, o);
                    uint32_t nt2 = umax32(umin32(t1, o1), umax32(t2, o2));
                    t1 = umax32(t1, o1);
                    t2 = nt2;
                }
                if ((lane & 15) == 0)
                    partial[((size_t)grow << 6) + (bx - 32) * 2 + wc] = make_uint2(t1, t2);
            }
        }
    }

    // ---- col-side finalize ----
    if (off_diag) {
#pragma unroll
        for (int n = 0; n < 4; n++) {
            float c = cs0[n] + cs1[n];
            c += __shfl_xor(c, 16);
            c += __shfl_xor(c, 32);
            // merge the two top-2 halves
            uint32_t a1 = umax32(s1a[n], s1b[n]);
            uint32_t a2 = umax32(umin32(s1a[n], s1b[n]), umax32(s2a[n], s2b[n]));
            if (is_cross) {
#pragma unroll
                for (int o = 16; o < 64; o <<= 1) {
                    uint32_t o1 = __shfl_xor(a1, o);
                    uint32_t o2 = __shfl_xor(a2, o);
                    uint32_t nt2 = umax32(umin32(a1, o1), umax32(a2, o2));
                    a1 = umax32(a1, o1);
                    a2 = nt2;
                }
            }
            if (lane < 16) {
                int gcol = bcol + wc * 64 + n * 16 + lane;
                atomicAdd(&rowsum[gcol], c);
                if (is_cross)
                    partial[((size_t)gcol << 6) + by * 2 + wr] = make_uint2(a1, a2);
            }
        }
    }
}

// ------- Kernel 2: top-10 + loss + fused final reduce ------------------
// 256 blocks x 32 rows; per-block partial sum -> 256 atomics to out.
__global__ __launch_bounds__(256) void topk_loss_kernel(const uint2* __restrict__ partial,
                                                        const float* __restrict__ pos_sim,
                                                        const float* __restrict__ rowsum,
                                                        float* __restrict__ out)
{
    int wv   = threadIdx.x >> 6;
    int lane = threadIdx.x & 63;
    float lsum = 0.f;

    for (int rr = 0; rr < 8; rr++) {
        int i = blockIdx.x * 32 + wv * 8 + rr;

        uint2 p = partial[((size_t)i << 6) + lane];
        uint32_t t1 = p.x, t2 = p.y;

        int posidx = i & (HALF_N - 1);
        float S10 = 0.f; int posflag = 0;
#pragma unroll
        for (int tc = 0; tc < 10; tc++) {
            uint32_t b = umax32(t1, t2);
#pragma unroll
            for (int o = 32; o; o >>= 1)
                b = umax32(b, __shfl_xor(b, o));
            bool w1 = (b == t1);
            bool w2 = (b == t2);
            t1 = w1 ? t2 : t1;
            t2 = (w1 | w2) ? 0u : t2;

            int idx = 4095 - (int)(b & 0xFFFFu);
            S10 += decode_key(b >> 16);
            posflag |= (idx == posidx) ? 1 : 0;
        }

        if (lane == 0) {
            float ps  = pos_sim[i];
            float lse = logf(rowsum[i]);
            float L   = 1.0f + 0.75f * (10 - posflag);
            float sll = INV_TAU * (ps + 0.75f * (S10 - posflag * ps));
            lsum += L * lse - sll;
        }
    }

    __shared__ float bsum[4];
    if (lane == 0) bsum[wv] = lsum;
    __syncthreads();
    if (threadIdx.x == 0)
        atomicAdd(out, (bsum[0] + bsum[1] + bsum[2] + bsum[3]) * (1.0f / N_TOTAL));
}

extern "C" void kernel_launch(void* const* d_in, const int* in_sizes, int n_in,
                              void* d_out, int out_size, void* d_ws, size_t ws_size,
                              hipStream_t stream)
{
    const float* z1 = (const float*)d_in[0];
    const float* z2 = (const float*)d_in[1];
    float* out = (float*)d_out;

    char* ws = (char*)d_ws;
    char*   zq      = ws;                              //  4 MB   8192x512 int8
    float*  rowsum  = (float*)(ws + 4194304);          // 32 KB
    float*  pos_sim = (float*)(ws + 4227072);          // 32 KB
    float*  inv_e   = (float*)(ws + 4259840);          // 32 KB
    uint2*  partial = (uint2*)(ws + 4292608);          //  4 MB   8192x64 uint2

    norm_kernel<<<N_TOTAL / 4, 256, 0, stream>>>(z1, z2, zq, inv_e, rowsum, out);
    gemm_kernel<<<2080, 256, 0, stream>>>(zq, inv_e, rowsum, partial, pos_sim);
    topk_loss_kernel<<<N_TOTAL / 32, 256, 0, stream>>>(partial, pos_sim, rowsum, out);
}

// Round 15
// 95.536 us; speedup vs baseline: 1.4511x; 1.4511x over previous
//
#include <hip/hip_runtime.h>
#include <hip/hip_bf16.h>
#include <stdint.h>

#define N_TOTAL 8192
#define HALF_N  4096
#define DIM     512
#define INV_TAU (1.0f/0.07f)
// exp2 fold: e = exp2(sim * INV_TAU * log2e); SCALE^2 = INV_TAU*log2e
#define EXP2_SCALE  4.5398160046388386f     /* sqrt(20.60992915555662) */
#define SIM_FROM_VE 0.0485203026391962f     /* 0.07 * ln2 */

typedef __attribute__((ext_vector_type(4))) int   i32x4;

#define AS1 __attribute__((address_space(1)))
#define AS3 __attribute__((address_space(3)))

__device__ __forceinline__ uint32_t umax32(uint32_t a, uint32_t b) { return a > b ? a : b; }
__device__ __forceinline__ uint32_t umin32(uint32_t a, uint32_t b) { return a < b ? a : b; }

__device__ __forceinline__ float decode_key(uint32_t key)
{
    ushort h = (key & 0x8000u) ? (ushort)(key ^ 0x8000u) : (ushort)(key ^ 0xFFFFu);
    return (float)(*(_Float16*)&h);
}

// ------- Kernel 0: normalize -> int8 quantize; inv_e = EXP2_SCALE/|q|;
//         zero rowsum and out ------------------------------------------
__global__ __launch_bounds__(256) void norm_kernel(const float* __restrict__ z1,
                                                   const float* __restrict__ z2,
                                                   char* __restrict__ zq,
                                                   float* __restrict__ inv_e,
                                                   float* __restrict__ rowsum,
                                                   float* __restrict__ out)
{
    if (threadIdx.x < 4) rowsum[blockIdx.x * 4 + threadIdx.x] = 0.f;
    if (blockIdx.x == 0 && threadIdx.x == 0) out[0] = 0.f;

    int row  = blockIdx.x * 4 + (threadIdx.x >> 6);
    int lane = threadIdx.x & 63;
    const float* src = (row < HALF_N) ? (z1 + (size_t)row * DIM)
                                      : (z2 + (size_t)(row - HALF_N) * DIM);
    const float4* p = (const float4*)src;
    float4 a = p[lane * 2];
    float4 b = p[lane * 2 + 1];
    float ss = a.x*a.x + a.y*a.y + a.z*a.z + a.w*a.w
             + b.x*b.x + b.y*b.y + b.z*b.z + b.w*b.w;
#pragma unroll
    for (int o = 1; o < 64; o <<= 1) ss += __shfl_xor(ss, o);
    float sc = 127.0f / fmaxf(sqrtf(ss), 1e-12f);

    float v[8] = {a.x*sc, a.y*sc, a.z*sc, a.w*sc, b.x*sc, b.y*sc, b.z*sc, b.w*sc};
    char c8[8];
    int qq = 0;
#pragma unroll
    for (int j = 0; j < 8; j++) {
        int qi = (int)rintf(v[j]);
        qq += qi * qi;
        c8[j] = (char)qi;
    }
#pragma unroll
    for (int o = 1; o < 64; o <<= 1) qq += __shfl_xor(qq, o);
    if (lane == 0) inv_e[row] = EXP2_SCALE / sqrtf(fmaxf((float)qq, 1.0f));

    *(uint2*)(zq + (size_t)row * DIM + lane * 8) = *(const uint2*)c8;
}

// ------- Kernel 1: upper-triangle 128x128 int8 MFMA GEMM (R12 core) ----
// R15: launch_bounds back to (256,4) — R14's (256,5) capped VGPR at 48
// and spilled the epilogue to scratch (WRITE_SIZE 16->154 MB). Keep the
// 2-way chain split + exp2 fold, which fit comfortably in the 128 cap.
__global__ __launch_bounds__(256, 4) void gemm_kernel(const char* __restrict__ zq,
                                                      const float* __restrict__ inv_e,
                                                      float* __restrict__ rowsum,
                                                      uint2* __restrict__ partial,
                                                      float* __restrict__ pos_sim)
{
    // XCD-aware swizzle: 2080 = 8 * 260, bijective
    int orig = blockIdx.x;
    int bid  = (orig & 7) * 260 + (orig >> 3);

    // triangular decode: bid -> (by, bx), bx >= by
    int by = (int)(64.5f - sqrtf(4160.25f - 2.0f * (float)bid));
    int off = 64 * by - (by * (by - 1)) / 2;
    if (off > bid) { --by; off = 64 * by - (by * (by - 1)) / 2; }
    else {
        int offn = 64 * (by + 1) - ((by + 1) * by) / 2;
        if (offn <= bid) { ++by; off = offn; }
    }
    int bx = by + (bid - off);

    const int brow = by * 128;
    const int bcol = bx * 128;

    __shared__ char As[2][128 * 64];   // 8 KB per buffer
    __shared__ char Bs[2][128 * 64];   // 32 KB total

    const int t    = threadIdx.x;
    const int w    = t >> 6;
    const int lane = t & 63;
    const int wr   = w >> 1, wc = w & 1;       // 2x2 waves of 64x64

    i32x4 acc[4][4] = {};

    const int c0 = t, c1 = 256 + t;
    const int r0 = c0 >> 2, r1 = c1 >> 2;
    const int q0 = (c0 & 3) ^ ((r0 >> 1) & 3);
    const int q1 = (c1 & 3) ^ ((r1 >> 1) & 3);
    const size_t gaA0 = (size_t)(brow + r0) * DIM + q0 * 16;
    const size_t gaA1 = (size_t)(brow + r1) * DIM + q1 * 16;
    const size_t gaB0 = (size_t)(bcol + r0) * DIM + q0 * 16;
    const size_t gaB1 = (size_t)(bcol + r1) * DIM + q1 * 16;
    const int l0 = (w * 64) * 16;
    const int l1 = (256 + w * 64) * 16;

#define STAGE(buf, ko) do {                                                        \
    __builtin_amdgcn_global_load_lds((const AS1 uint32_t*)(zq + gaA0 + (ko)),      \
        (AS3 uint32_t*)((char*)As[buf] + l0), 16, 0, 0);                           \
    __builtin_amdgcn_global_load_lds((const AS1 uint32_t*)(zq + gaA1 + (ko)),      \
        (AS3 uint32_t*)((char*)As[buf] + l1), 16, 0, 0);                           \
    __builtin_amdgcn_global_load_lds((const AS1 uint32_t*)(zq + gaB0 + (ko)),      \
        (AS3 uint32_t*)((char*)Bs[buf] + l0), 16, 0, 0);                           \
    __builtin_amdgcn_global_load_lds((const AS1 uint32_t*)(zq + gaB1 + (ko)),      \
        (AS3 uint32_t*)((char*)Bs[buf] + l1), 16, 0, 0);                           \
} while (0)

    STAGE(0, 0);
    __syncthreads();

    int cur = 0;
    for (int kt = 0; kt < DIM / 64; ++kt) {
        if (kt + 1 < DIM / 64) STAGE(cur ^ 1, (kt + 1) * 64);

        i32x4 av[4], bv[4];
#pragma unroll
        for (int m = 0; m < 4; m++) {
            int ro = wr * 64 + m * 16 + (lane & 15);
            int s  = (lane >> 4) ^ ((ro >> 1) & 3);
            av[m] = *(const i32x4*)(As[cur] + ro * 64 + s * 16);
        }
#pragma unroll
        for (int n = 0; n < 4; n++) {
            int ro = wc * 64 + n * 16 + (lane & 15);
            int s  = (lane >> 4) ^ ((ro >> 1) & 3);
            bv[n] = *(const i32x4*)(Bs[cur] + ro * 64 + s * 16);
        }
#pragma unroll
        for (int m = 0; m < 4; m++)
#pragma unroll
            for (int n = 0; n < 4; n++)
                acc[m][n] = __builtin_amdgcn_mfma_i32_16x16x64_i8(av[m], bv[n], acc[m][n], 0, 0, 0);

        __syncthreads();
        cur ^= 1;
    }
#undef STAGE

    const bool is_cross = (brow < HALF_N) && (bcol >= HALF_N);
    const bool off_diag = (bx != by);

    float invc[4];
#pragma unroll
    for (int n = 0; n < 4; n++)
        invc[n] = inv_e[bcol + wc * 64 + n * 16 + (lane & 15)];

    // 2-way split accumulators (halve the loop-carried dep chains)
    float    cs0[4] = {0,0,0,0}, cs1[4] = {0,0,0,0};
    uint32_t s1a[4] = {0,0,0,0}, s2a[4] = {0,0,0,0};
    uint32_t s1b[4] = {0,0,0,0}, s2b[4] = {0,0,0,0};

    // ---- single fused epilogue pass ----
#pragma unroll
    for (int m = 0; m < 4; m++) {
#pragma unroll
        for (int r = 0; r < 4; r++) {
            int grow = brow + wr * 64 + m * 16 + ((lane >> 4) << 2) + r;
            float invr = inv_e[grow];
            float rs = 0.f;
            uint32_t t1 = 0u, t2 = 0u;
#pragma unroll
            for (int n = 0; n < 4; n++) {
                int gcol = bcol + wc * 64 + n * 16 + (lane & 15);
                float ve = (float)acc[m][n][r] * (invr * invc[n]);   // sim*INV_TAU*log2e
                float e  = (grow == gcol) ? 0.f : __builtin_exp2f(ve);
                rs += e;
                if (m < 2) cs0[n] += e; else cs1[n] += e;
                if (is_cross) {
                    float v = ve * SIM_FROM_VE;                      // raw sim
                    int cidx = gcol - HALF_N;
                    ushort h;
                    *(_Float16*)&h = (_Float16)v;
                    uint32_t key = ((uint32_t)(ushort)(h ^ (ushort)((ushort)((short)h >> 15) | 0x8000))) << 16;
                    uint32_t xr = key | (uint32_t)(4095 - cidx);
                    uint32_t mn = umin32(t1, xr);
                    t1 = umax32(t1, xr);
                    t2 = umax32(t2, mn);
                    uint32_t xc = key | (uint32_t)(4095 - grow);
                    if (m < 2) {
                        mn = umin32(s1a[n], xc); s1a[n] = umax32(s1a[n], xc); s2a[n] = umax32(s2a[n], mn);
                    } else {
                        mn = umin32(s1b[n], xc); s1b[n] = umax32(s1b[n], xc); s2b[n] = umax32(s2b[n], mn);
                    }
                    if (cidx == grow) { pos_sim[grow] = v; pos_sim[gcol] = v; }
                }
            }
            rs += __shfl_xor(rs, 1);
            rs += __shfl_xor(rs, 2);
            rs += __shfl_xor(rs, 4);
            rs += __shfl_xor(rs, 8);
            if ((lane & 15) == 0) atomicAdd(&rowsum[grow], rs);

            if (is_cross) {
#pragma unroll
                for (int o = 1; o < 16; o <<= 1) {
                    uint32_t o1 = __shfl_xor(t1, o);
                    uint32_t o2 = __shfl_xor(t2, o);
                    uint32_t nt2 = umax32(umin32(t1, o1), umax32(t2, o2));
                    t1 = umax32(t1, o1);
                    t2 = nt2;
                }
                if ((lane & 15) == 0)
                    partial[((size_t)grow << 6) + (bx - 32) * 2 + wc] = make_uint2(t1, t2);
            }
        }
    }

    // ---- col-side finalize ----
    if (off_diag) {
#pragma unroll
        for (int n = 0; n < 4; n++) {
            float c = cs0[n] + cs1[n];
            c += __shfl_xor(c, 16);
            c += __shfl_xor(c, 32);
            // merge the two top-2 halves
            uint32_t a1 = umax32(s1a[n], s1b[n]);
            uint32_t a2 = umax32(umin32(s1a[n], s1b[n]), umax32(s2a[n], s2b[n]));
            if (is_cross) {
#pragma unroll
                for (int o = 16; o < 64; o <<= 1) {
                    uint32_t o1 = __shfl_xor(a1, o);
                    uint32_t o2 = __shfl_xor(a2, o);
                    uint32_t nt2 = umax32(umin32(a1, o1), umax32(a2, o2));
                    a1 = umax32(a1, o1);
                    a2 = nt2;
                }
            }
            if (lane < 16) {
                int gcol = bcol + wc * 64 + n * 16 + lane;
                atomicAdd(&rowsum[gcol], c);
                if (is_cross)
                    partial[((size_t)gcol << 6) + by * 2 + wr] = make_uint2(a1, a2);
            }
        }
    }
}

// ------- Kernel 2: top-10 + loss + fused final reduce ------------------
// 256 blocks x 32 rows; per-block partial sum -> 256 atomics to out.
__global__ __launch_bounds__(256) void topk_loss_kernel(const uint2* __restrict__ partial,
                                                        const float* __restrict__ pos_sim,
                                                        const float* __restrict__ rowsum,
                                                        float* __restrict__ out)
{
    int wv   = threadIdx.x >> 6;
    int lane = threadIdx.x & 63;
    float lsum = 0.f;

    for (int rr = 0; rr < 8; rr++) {
        int i = blockIdx.x * 32 + wv * 8 + rr;

        uint2 p = partial[((size_t)i << 6) + lane];
        uint32_t t1 = p.x, t2 = p.y;

        int posidx = i & (HALF_N - 1);
        float S10 = 0.f; int posflag = 0;
#pragma unroll
        for (int tc = 0; tc < 10; tc++) {
            uint32_t b = umax32(t1, t2);
#pragma unroll
            for (int o = 32; o; o >>= 1)
                b = umax32(b, __shfl_xor(b, o));
            bool w1 = (b == t1);
            bool w2 = (b == t2);
            t1 = w1 ? t2 : t1;
            t2 = (w1 | w2) ? 0u : t2;

            int idx = 4095 - (int)(b & 0xFFFFu);
            S10 += decode_key(b >> 16);
            posflag |= (idx == posidx) ? 1 : 0;
        }

        if (lane == 0) {
            float ps  = pos_sim[i];
            float lse = logf(rowsum[i]);
            float L   = 1.0f + 0.75f * (10 - posflag);
            float sll = INV_TAU * (ps + 0.75f * (S10 - posflag * ps));
            lsum += L * lse - sll;
        }
    }

    __shared__ float bsum[4];
    if (lane == 0) bsum[wv] = lsum;
    __syncthreads();
    if (threadIdx.x == 0)
        atomicAdd(out, (bsum[0] + bsum[1] + bsum[2] + bsum[3]) * (1.0f / N_TOTAL));
}

extern "C" void kernel_launch(void* const* d_in, const int* in_sizes, int n_in,
                              void* d_out, int out_size, void* d_ws, size_t ws_size,
                              hipStream_t stream)
{
    const float* z1 = (const float*)d_in[0];
    const float* z2 = (const float*)d_in[1];
    float* out = (float*)d_out;

    char* ws = (char*)d_ws;
    char*   zq      = ws;                              //  4 MB   8192x512 int8
    float*  rowsum  = (float*)(ws + 4194304);          // 32 KB
    float*  pos_sim = (float*)(ws + 4227072);          // 32 KB
    float*  inv_e   = (float*)(ws + 4259840);          // 32 KB
    uint2*  partial = (uint2*)(ws + 4292608);          //  4 MB   8192x64 uint2

    norm_kernel<<<N_TOTAL / 4, 256, 0, stream>>>(z1, z2, zq, inv_e, rowsum, out);
    gemm_kernel<<<2080, 256, 0, stream>>>(zq, inv_e, rowsum, partial, pos_sim);
    topk_loss_kernel<<<N_TOTAL / 32, 256, 0, stream>>>(partial, pos_sim, rowsum, out);
}

// Round 16
// 87.747 us; speedup vs baseline: 1.5799x; 1.0888x over previous
//
#include <hip/hip_runtime.h>
#include <hip/hip_bf16.h>
#include <stdint.h>

#define N_TOTAL 8192
#define HALF_N  4096
#define DIM     512
#define INV_TAU (1.0f/0.07f)
// exp2 fold: e = exp2(sim * INV_TAU * log2e); SCALE^2 = INV_TAU*log2e
#define EXP2_SCALE  4.5398160046388386f     /* sqrt(20.60992915555662) */
#define SIM_FROM_VE 0.0485203026391962f     /* 0.07 * ln2 */

typedef __attribute__((ext_vector_type(4))) int   i32x4;

#define AS1 __attribute__((address_space(1)))
#define AS3 __attribute__((address_space(3)))

__device__ __forceinline__ uint32_t umax32(uint32_t a, uint32_t b) { return a > b ? a : b; }
__device__ __forceinline__ uint32_t umin32(uint32_t a, uint32_t b) { return a < b ? a : b; }

__device__ __forceinline__ float decode_key(uint32_t key)
{
    ushort h = (key & 0x8000u) ? (ushort)(key ^ 0x8000u) : (ushort)(key ^ 0xFFFFu);
    return (float)(*(_Float16*)&h);
}

// ------- Kernel 0: normalize -> int8 quantize; inv_e = EXP2_SCALE/|q|;
//         zero rowsum --------------------------------------------------
__global__ __launch_bounds__(256) void norm_kernel(const float* __restrict__ z1,
                                                   const float* __restrict__ z2,
                                                   char* __restrict__ zq,
                                                   float* __restrict__ inv_e,
                                                   float* __restrict__ rowsum)
{
    if (threadIdx.x < 4) rowsum[blockIdx.x * 4 + threadIdx.x] = 0.f;

    int row  = blockIdx.x * 4 + (threadIdx.x >> 6);
    int lane = threadIdx.x & 63;
    const float* src = (row < HALF_N) ? (z1 + (size_t)row * DIM)
                                      : (z2 + (size_t)(row - HALF_N) * DIM);
    const float4* p = (const float4*)src;
    float4 a = p[lane * 2];
    float4 b = p[lane * 2 + 1];
    float ss = a.x*a.x + a.y*a.y + a.z*a.z + a.w*a.w
             + b.x*b.x + b.y*b.y + b.z*b.z + b.w*b.w;
#pragma unroll
    for (int o = 1; o < 64; o <<= 1) ss += __shfl_xor(ss, o);
    float sc = 127.0f / fmaxf(sqrtf(ss), 1e-12f);

    float v[8] = {a.x*sc, a.y*sc, a.z*sc, a.w*sc, b.x*sc, b.y*sc, b.z*sc, b.w*sc};
    char c8[8];
    int qq = 0;
#pragma unroll
    for (int j = 0; j < 8; j++) {
        int qi = (int)rintf(v[j]);
        qq += qi * qi;
        c8[j] = (char)qi;
    }
#pragma unroll
    for (int o = 1; o < 64; o <<= 1) qq += __shfl_xor(qq, o);
    if (lane == 0) inv_e[row] = EXP2_SCALE / sqrtf(fmaxf((float)qq, 1.0f));

    *(uint2*)(zq + (size_t)row * DIM + lane * 8) = *(const uint2*)c8;
}

// ------- Kernel 1: upper-triangle 128x128 int8 MFMA GEMM (R15, best) ---
__global__ __launch_bounds__(256, 4) void gemm_kernel(const char* __restrict__ zq,
                                                      const float* __restrict__ inv_e,
                                                      float* __restrict__ rowsum,
                                                      uint2* __restrict__ partial,
                                                      float* __restrict__ pos_sim)
{
    // XCD-aware swizzle: 2080 = 8 * 260, bijective
    int orig = blockIdx.x;
    int bid  = (orig & 7) * 260 + (orig >> 3);

    // triangular decode: bid -> (by, bx), bx >= by
    int by = (int)(64.5f - sqrtf(4160.25f - 2.0f * (float)bid));
    int off = 64 * by - (by * (by - 1)) / 2;
    if (off > bid) { --by; off = 64 * by - (by * (by - 1)) / 2; }
    else {
        int offn = 64 * (by + 1) - ((by + 1) * by) / 2;
        if (offn <= bid) { ++by; off = offn; }
    }
    int bx = by + (bid - off);

    const int brow = by * 128;
    const int bcol = bx * 128;

    __shared__ char As[2][128 * 64];   // 8 KB per buffer
    __shared__ char Bs[2][128 * 64];   // 32 KB total

    const int t    = threadIdx.x;
    const int w    = t >> 6;
    const int lane = t & 63;
    const int wr   = w >> 1, wc = w & 1;       // 2x2 waves of 64x64

    i32x4 acc[4][4] = {};

    const int c0 = t, c1 = 256 + t;
    const int r0 = c0 >> 2, r1 = c1 >> 2;
    const int q0 = (c0 & 3) ^ ((r0 >> 1) & 3);
    const int q1 = (c1 & 3) ^ ((r1 >> 1) & 3);
    const size_t gaA0 = (size_t)(brow + r0) * DIM + q0 * 16;
    const size_t gaA1 = (size_t)(brow + r1) * DIM + q1 * 16;
    const size_t gaB0 = (size_t)(bcol + r0) * DIM + q0 * 16;
    const size_t gaB1 = (size_t)(bcol + r1) * DIM + q1 * 16;
    const int l0 = (w * 64) * 16;
    const int l1 = (256 + w * 64) * 16;

#define STAGE(buf, ko) do {                                                        \
    __builtin_amdgcn_global_load_lds((const AS1 uint32_t*)(zq + gaA0 + (ko)),      \
        (AS3 uint32_t*)((char*)As[buf] + l0), 16, 0, 0);                           \
    __builtin_amdgcn_global_load_lds((const AS1 uint32_t*)(zq + gaA1 + (ko)),      \
        (AS3 uint32_t*)((char*)As[buf] + l1), 16, 0, 0);                           \
    __builtin_amdgcn_global_load_lds((const AS1 uint32_t*)(zq + gaB0 + (ko)),      \
        (AS3 uint32_t*)((char*)Bs[buf] + l0), 16, 0, 0);                           \
    __builtin_amdgcn_global_load_lds((const AS1 uint32_t*)(zq + gaB1 + (ko)),      \
        (AS3 uint32_t*)((char*)Bs[buf] + l1), 16, 0, 0);                           \
} while (0)

    STAGE(0, 0);
    __syncthreads();

    int cur = 0;
    for (int kt = 0; kt < DIM / 64; ++kt) {
        if (kt + 1 < DIM / 64) STAGE(cur ^ 1, (kt + 1) * 64);

        i32x4 av[4], bv[4];
#pragma unroll
        for (int m = 0; m < 4; m++) {
            int ro = wr * 64 + m * 16 + (lane & 15);
            int s  = (lane >> 4) ^ ((ro >> 1) & 3);
            av[m] = *(const i32x4*)(As[cur] + ro * 64 + s * 16);
        }
#pragma unroll
        for (int n = 0; n < 4; n++) {
            int ro = wc * 64 + n * 16 + (lane & 15);
            int s  = (lane >> 4) ^ ((ro >> 1) & 3);
            bv[n] = *(const i32x4*)(Bs[cur] + ro * 64 + s * 16);
        }
#pragma unroll
        for (int m = 0; m < 4; m++)
#pragma unroll
            for (int n = 0; n < 4; n++)
                acc[m][n] = __builtin_amdgcn_mfma_i32_16x16x64_i8(av[m], bv[n], acc[m][n], 0, 0, 0);

        __syncthreads();
        cur ^= 1;
    }
#undef STAGE

    const bool is_cross = (brow < HALF_N) && (bcol >= HALF_N);
    const bool off_diag = (bx != by);

    float invc[4];
#pragma unroll
    for (int n = 0; n < 4; n++)
        invc[n] = inv_e[bcol + wc * 64 + n * 16 + (lane & 15)];

    // 2-way split accumulators (halve the loop-carried dep chains)
    float    cs0[4] = {0,0,0,0}, cs1[4] = {0,0,0,0};
    uint32_t s1a[4] = {0,0,0,0}, s2a[4] = {0,0,0,0};
    uint32_t s1b[4] = {0,0,0,0}, s2b[4] = {0,0,0,0};

    // ---- single fused epilogue pass ----
#pragma unroll
    for (int m = 0; m < 4; m++) {
#pragma unroll
        for (int r = 0; r < 4; r++) {
            int grow = brow + wr * 64 + m * 16 + ((lane >> 4) << 2) + r;
            float invr = inv_e[grow];
            float rs = 0.f;
            uint32_t t1 = 0u, t2 = 0u;
#pragma unroll
            for (int n = 0; n < 4; n++) {
                int gcol = bcol + wc * 64 + n * 16 + (lane & 15);
                float ve = (float)acc[m][n][r] * (invr * invc[n]);   // sim*INV_TAU*log2e
                float e  = (grow == gcol) ? 0.f : __builtin_exp2f(ve);
                rs += e;
                if (m < 2) cs0[n] += e; else cs1[n] += e;
                if (is_cross) {
                    float v = ve * SIM_FROM_VE;                      // raw sim
                    int cidx = gcol - HALF_N;
                    ushort h;
                    *(_Float16*)&h = (_Float16)v;
                    uint32_t key = ((uint32_t)(ushort)(h ^ (ushort)((ushort)((short)h >> 15) | 0x8000))) << 16;
                    uint32_t xr = key | (uint32_t)(4095 - cidx);
                    uint32_t mn = umin32(t1, xr);
                    t1 = umax32(t1, xr);
                    t2 = umax32(t2, mn);
                    uint32_t xc = key | (uint32_t)(4095 - grow);
                    if (m < 2) {
                        mn = umin32(s1a[n], xc); s1a[n] = umax32(s1a[n], xc); s2a[n] = umax32(s2a[n], mn);
                    } else {
                        mn = umin32(s1b[n], xc); s1b[n] = umax32(s1b[n], xc); s2b[n] = umax32(s2b[n], mn);
                    }
                    if (cidx == grow) { pos_sim[grow] = v; pos_sim[gcol] = v; }
                }
            }
            rs += __shfl_xor(rs, 1);
            rs += __shfl_xor(rs, 2);
            rs += __shfl_xor(rs, 4);
            rs += __shfl_xor(rs, 8);
            if ((lane & 15) == 0) atomicAdd(&rowsum[grow], rs);

            if (is_cross) {
#pragma unroll
                for (int o = 1; o < 16; o <<= 1) {
                    uint32_t o1 = __shfl_xor(t1, o);
                    uint32_t o2 = __shfl_xor(t2, o);
                    uint32_t nt2 = umax32(umin32(t1, o1), umax32(t2, o2));
                    t1 = umax32(t1, o1);
                    t2 = nt2;
                }
                if ((lane & 15) == 0)
                    partial[((size_t)grow << 6) + (bx - 32) * 2 + wc] = make_uint2(t1, t2);
            }
        }
    }

    // ---- col-side finalize ----
    if (off_diag) {
#pragma unroll
        for (int n = 0; n < 4; n++) {
            float c = cs0[n] + cs1[n];
            c += __shfl_xor(c, 16);
            c += __shfl_xor(c, 32);
            // merge the two top-2 halves
            uint32_t a1 = umax32(s1a[n], s1b[n]);
            uint32_t a2 = umax32(umin32(s1a[n], s1b[n]), umax32(s2a[n], s2b[n]));
            if (is_cross) {
#pragma unroll
                for (int o = 16; o < 64; o <<= 1) {
                    uint32_t o1 = __shfl_xor(a1, o);
                    uint32_t o2 = __shfl_xor(a2, o);
                    uint32_t nt2 = umax32(umin32(a1, o1), umax32(a2, o2));
                    a1 = umax32(a1, o1);
                    a2 = nt2;
                }
            }
            if (lane < 16) {
                int gcol = bcol + wc * 64 + n * 16 + lane;
                atomicAdd(&rowsum[gcol], c);
                if (is_cross)
                    partial[((size_t)gcol << 6) + by * 2 + wr] = make_uint2(a1, a2);
            }
        }
    }
}

// ------- Kernel 2: per-row top-10 + per-row loss (R12 structure) -------
// 2048 blocks x 4 rows, one row per wave; writes contrib[] (no atomics).
__global__ __launch_bounds__(256) void topk_loss_kernel(const uint2* __restrict__ partial,
                                                        const float* __restrict__ pos_sim,
                                                        const float* __restrict__ rowsum,
                                                        float* __restrict__ contrib)
{
    int i    = blockIdx.x * 4 + (threadIdx.x >> 6);
    int lane = threadIdx.x & 63;

    uint2 p = partial[((size_t)i << 6) + lane];
    uint32_t t1 = p.x, t2 = p.y;

    int posidx = i & (HALF_N - 1);
    float S10 = 0.f; int posflag = 0;
#pragma unroll
    for (int tc = 0; tc < 10; tc++) {
        uint32_t b = umax32(t1, t2);
#pragma unroll
        for (int o = 32; o; o >>= 1)
            b = umax32(b, __shfl_xor(b, o));
        bool w1 = (b == t1);
        bool w2 = (b == t2);
        t1 = w1 ? t2 : t1;
        t2 = (w1 | w2) ? 0u : t2;

        int idx = 4095 - (int)(b & 0xFFFFu);
        S10 += decode_key(b >> 16);
        posflag |= (idx == posidx) ? 1 : 0;
    }

    if (lane == 0) {
        float ps  = pos_sim[i];
        float lse = logf(rowsum[i]);
        float L   = 1.0f + 0.75f * (10 - posflag);
        float sll = INV_TAU * (ps + 0.75f * (S10 - posflag * ps));
        contrib[i] = L * lse - sll;
    }
}

// ------- Kernel 3: deterministic final reduce --------------------------
__global__ __launch_bounds__(256) void reduce_kernel(const float* __restrict__ contrib,
                                                     float* __restrict__ out)
{
    int t = threadIdx.x;
    float s = 0.f;
    for (int j = t; j < N_TOTAL; j += 256) s += contrib[j];
#pragma unroll
    for (int o = 1; o < 64; o <<= 1) s += __shfl_xor(s, o);
    __shared__ float wsum[4];
    if ((t & 63) == 0) wsum[t >> 6] = s;
    __syncthreads();
    if (t == 0) out[0] = (wsum[0] + wsum[1] + wsum[2] + wsum[3]) * (1.0f / N_TOTAL);
}

extern "C" void kernel_launch(void* const* d_in, const int* in_sizes, int n_in,
                              void* d_out, int out_size, void* d_ws, size_t ws_size,
                              hipStream_t stream)
{
    const float* z1 = (const float*)d_in[0];
    const float* z2 = (const float*)d_in[1];
    float* out = (float*)d_out;

    char* ws = (char*)d_ws;
    char*   zq      = ws;                              //  4 MB   8192x512 int8
    float*  rowsum  = (float*)(ws + 4194304);          // 32 KB
    float*  pos_sim = (float*)(ws + 4227072);          // 32 KB
    float*  inv_e   = (float*)(ws + 4259840);          // 32 KB
    uint2*  partial = (uint2*)(ws + 4292608);          //  4 MB   8192x64 uint2
    float*  contrib = (float*)(ws + 8486912);          // 32 KB

    norm_kernel<<<N_TOTAL / 4, 256, 0, stream>>>(z1, z2, zq, inv_e, rowsum);
    gemm_kernel<<<2080, 256, 0, stream>>>(zq, inv_e, rowsum, partial, pos_sim);
    topk_loss_kernel<<<N_TOTAL / 4, 256, 0, stream>>>(partial, pos_sim, rowsum, contrib);
    reduce_kernel<<<1, 256, 0, stream>>>(contrib, out);
}

// Round 18
// 85.252 us; speedup vs baseline: 1.6261x; 1.0293x over previous
//
#include <hip/hip_runtime.h>
#include <hip/hip_bf16.h>
#include <stdint.h>

#define N_TOTAL 8192
#define HALF_N  4096
#define DIM     512
#define INV_TAU (1.0f/0.07f)
// exp2 fold: e = exp2(sim * INV_TAU * log2e); SCALE^2 = INV_TAU*log2e
#define EXP2_SCALE  4.5398160046388386f     /* sqrt(20.60992915555662) */
#define SIM_FROM_VE 0.0485203026391962f     /* 0.07 * ln2 */

typedef __attribute__((ext_vector_type(4))) int   i32x4;

#define AS1 __attribute__((address_space(1)))
#define AS3 __attribute__((address_space(3)))

__device__ __forceinline__ uint32_t umax32(uint32_t a, uint32_t b) { return a > b ? a : b; }
__device__ __forceinline__ uint32_t umin32(uint32_t a, uint32_t b) { return a < b ? a : b; }

// DPP row_shr step: lane l reads lane l-N within its 16-lane row;
// out-of-row reads 0 (bound_ctrl=1) — identity for f32-add and u32-max.
#define DPP_SHR_F32(x, ctrl) \
    __int_as_float(__builtin_amdgcn_update_dpp(0, __float_as_int(x), (ctrl), 0xf, 0xf, true))
#define DPP_SHR_U32(x, ctrl) \
    ((uint32_t)__builtin_amdgcn_update_dpp(0, (int)(x), (ctrl), 0xf, 0xf, true))

// one top-2 merge step with literal ctrl (DPP ctrl must be parse-time const)
#define TOP2_DPP_STEP(t1, t2, ctrl) do {                                           \
    uint32_t o1_ = DPP_SHR_U32(t1, ctrl);                                          \
    uint32_t o2_ = DPP_SHR_U32(t2, ctrl);                                          \
    uint32_t mn_ = umin32(t1, o1_);                                                \
    t1 = umax32(t1, o1_);                                                          \
    o2_ = umax32(t2, o2_);                                                         \
    t2 = umax32(mn_, o2_);                                                         \
} while (0)

__device__ __forceinline__ float decode_key(uint32_t key)
{
    ushort h = (key & 0x8000u) ? (ushort)(key ^ 0x8000u) : (ushort)(key ^ 0xFFFFu);
    return (float)(*(_Float16*)&h);
}

// ------- Kernel 0: normalize -> int8 quantize; inv_e = EXP2_SCALE/|q|;
//         zero rowsum --------------------------------------------------
__global__ __launch_bounds__(256) void norm_kernel(const float* __restrict__ z1,
                                                   const float* __restrict__ z2,
                                                   char* __restrict__ zq,
                                                   float* __restrict__ inv_e,
                                                   float* __restrict__ rowsum)
{
    if (threadIdx.x < 4) rowsum[blockIdx.x * 4 + threadIdx.x] = 0.f;

    int row  = blockIdx.x * 4 + (threadIdx.x >> 6);
    int lane = threadIdx.x & 63;
    const float* src = (row < HALF_N) ? (z1 + (size_t)row * DIM)
                                      : (z2 + (size_t)(row - HALF_N) * DIM);
    const float4* p = (const float4*)src;
    float4 a = p[lane * 2];
    float4 b = p[lane * 2 + 1];
    float ss = a.x*a.x + a.y*a.y + a.z*a.z + a.w*a.w
             + b.x*b.x + b.y*b.y + b.z*b.z + b.w*b.w;
#pragma unroll
    for (int o = 1; o < 64; o <<= 1) ss += __shfl_xor(ss, o);
    float sc = 127.0f / fmaxf(sqrtf(ss), 1e-12f);

    float v[8] = {a.x*sc, a.y*sc, a.z*sc, a.w*sc, b.x*sc, b.y*sc, b.z*sc, b.w*sc};
    char c8[8];
    int qq = 0;
#pragma unroll
    for (int j = 0; j < 8; j++) {
        int qi = (int)rintf(v[j]);
        qq += qi * qi;
        c8[j] = (char)qi;
    }
#pragma unroll
    for (int o = 1; o < 64; o <<= 1) qq += __shfl_xor(qq, o);
    if (lane == 0) inv_e[row] = EXP2_SCALE / sqrtf(fmaxf((float)qq, 1.0f));

    *(uint2*)(zq + (size_t)row * DIM + lane * 8) = *(const uint2*)c8;
}

// ------- Kernel 1: upper-triangle 128x128 int8 MFMA GEMM ---------------
// R18 (= R17 intent, fixed literals): epilogue intra-16-lane reductions
// (rs sum, top-2 merge) moved from shfl_xor (ds_swizzle, ~35cyc LDS
// latency, ~192/thread) to DPP row_shr cascades (VALU speed, zero LDS).
// Result lands in lane 15 of each 16-lane row; writer = (lane&15)==15.
__global__ __launch_bounds__(256, 4) void gemm_kernel(const char* __restrict__ zq,
                                                      const float* __restrict__ inv_e,
                                                      float* __restrict__ rowsum,
                                                      uint2* __restrict__ partial,
                                                      float* __restrict__ pos_sim)
{
    // XCD-aware swizzle: 2080 = 8 * 260, bijective
    int orig = blockIdx.x;
    int bid  = (orig & 7) * 260 + (orig >> 3);

    // triangular decode: bid -> (by, bx), bx >= by
    int by = (int)(64.5f - sqrtf(4160.25f - 2.0f * (float)bid));
    int off = 64 * by - (by * (by - 1)) / 2;
    if (off > bid) { --by; off = 64 * by - (by * (by - 1)) / 2; }
    else {
        int offn = 64 * (by + 1) - ((by + 1) * by) / 2;
        if (offn <= bid) { ++by; off = offn; }
    }
    int bx = by + (bid - off);

    const int brow = by * 128;
    const int bcol = bx * 128;

    __shared__ char As[2][128 * 64];   // 8 KB per buffer
    __shared__ char Bs[2][128 * 64];   // 32 KB total

    const int t    = threadIdx.x;
    const int w    = t >> 6;
    const int lane = t & 63;
    const int wr   = w >> 1, wc = w & 1;       // 2x2 waves of 64x64

    i32x4 acc[4][4] = {};

    const int c0 = t, c1 = 256 + t;
    const int r0 = c0 >> 2, r1 = c1 >> 2;
    const int q0 = (c0 & 3) ^ ((r0 >> 1) & 3);
    const int q1 = (c1 & 3) ^ ((r1 >> 1) & 3);
    const size_t gaA0 = (size_t)(brow + r0) * DIM + q0 * 16;
    const size_t gaA1 = (size_t)(brow + r1) * DIM + q1 * 16;
    const size_t gaB0 = (size_t)(bcol + r0) * DIM + q0 * 16;
    const size_t gaB1 = (size_t)(bcol + r1) * DIM + q1 * 16;
    const int l0 = (w * 64) * 16;
    const int l1 = (256 + w * 64) * 16;

#define STAGE(buf, ko) do {                                                        \
    __builtin_amdgcn_global_load_lds((const AS1 uint32_t*)(zq + gaA0 + (ko)),      \
        (AS3 uint32_t*)((char*)As[buf] + l0), 16, 0, 0);                           \
    __builtin_amdgcn_global_load_lds((const AS1 uint32_t*)(zq + gaA1 + (ko)),      \
        (AS3 uint32_t*)((char*)As[buf] + l1), 16, 0, 0);                           \
    __builtin_amdgcn_global_load_lds((const AS1 uint32_t*)(zq + gaB0 + (ko)),      \
        (AS3 uint32_t*)((char*)Bs[buf] + l0), 16, 0, 0);                           \
    __builtin_amdgcn_global_load_lds((const AS1 uint32_t*)(zq + gaB1 + (ko)),      \
        (AS3 uint32_t*)((char*)Bs[buf] + l1), 16, 0, 0);                           \
} while (0)

    STAGE(0, 0);
    __syncthreads();

    int cur = 0;
    for (int kt = 0; kt < DIM / 64; ++kt) {
        if (kt + 1 < DIM / 64) STAGE(cur ^ 1, (kt + 1) * 64);

        i32x4 av[4], bv[4];
#pragma unroll
        for (int m = 0; m < 4; m++) {
            int ro = wr * 64 + m * 16 + (lane & 15);
            int s  = (lane >> 4) ^ ((ro >> 1) & 3);
            av[m] = *(const i32x4*)(As[cur] + ro * 64 + s * 16);
        }
#pragma unroll
        for (int n = 0; n < 4; n++) {
            int ro = wc * 64 + n * 16 + (lane & 15);
            int s  = (lane >> 4) ^ ((ro >> 1) & 3);
            bv[n] = *(const i32x4*)(Bs[cur] + ro * 64 + s * 16);
        }
#pragma unroll
        for (int m = 0; m < 4; m++)
#pragma unroll
            for (int n = 0; n < 4; n++)
                acc[m][n] = __builtin_amdgcn_mfma_i32_16x16x64_i8(av[m], bv[n], acc[m][n], 0, 0, 0);

        __syncthreads();
        cur ^= 1;
    }
#undef STAGE

    const bool is_cross = (brow < HALF_N) && (bcol >= HALF_N);
    const bool off_diag = (bx != by);

    float invc[4];
#pragma unroll
    for (int n = 0; n < 4; n++)
        invc[n] = inv_e[bcol + wc * 64 + n * 16 + (lane & 15)];

    // 2-way split accumulators (halve the loop-carried dep chains)
    float    cs0[4] = {0,0,0,0}, cs1[4] = {0,0,0,0};
    uint32_t s1a[4] = {0,0,0,0}, s2a[4] = {0,0,0,0};
    uint32_t s1b[4] = {0,0,0,0}, s2b[4] = {0,0,0,0};

    // ---- single fused epilogue pass ----
#pragma unroll
    for (int m = 0; m < 4; m++) {
#pragma unroll
        for (int r = 0; r < 4; r++) {
            int grow = brow + wr * 64 + m * 16 + ((lane >> 4) << 2) + r;
            float invr = inv_e[grow];
            float rs = 0.f;
            uint32_t t1 = 0u, t2 = 0u;
#pragma unroll
            for (int n = 0; n < 4; n++) {
                int gcol = bcol + wc * 64 + n * 16 + (lane & 15);
                float ve = (float)acc[m][n][r] * (invr * invc[n]);   // sim*INV_TAU*log2e
                float e  = (grow == gcol) ? 0.f : __builtin_exp2f(ve);
                rs += e;
                if (m < 2) cs0[n] += e; else cs1[n] += e;
                if (is_cross) {
                    float v = ve * SIM_FROM_VE;                      // raw sim
                    int cidx = gcol - HALF_N;
                    ushort h;
                    *(_Float16*)&h = (_Float16)v;
                    uint32_t key = ((uint32_t)(ushort)(h ^ (ushort)((ushort)((short)h >> 15) | 0x8000))) << 16;
                    uint32_t xr = key | (uint32_t)(4095 - cidx);
                    uint32_t mn = umin32(t1, xr);
                    t1 = umax32(t1, xr);
                    t2 = umax32(t2, mn);
                    uint32_t xc = key | (uint32_t)(4095 - grow);
                    if (m < 2) {
                        mn = umin32(s1a[n], xc); s1a[n] = umax32(s1a[n], xc); s2a[n] = umax32(s2a[n], mn);
                    } else {
                        mn = umin32(s1b[n], xc); s1b[n] = umax32(s1b[n], xc); s2b[n] = umax32(s2b[n], mn);
                    }
                    if (cidx == grow) { pos_sim[grow] = v; pos_sim[gcol] = v; }
                }
            }
            // rs sum over the 16-lane row via DPP row_shr tree -> lane 15
            rs += DPP_SHR_F32(rs, 0x111);
            rs += DPP_SHR_F32(rs, 0x112);
            rs += DPP_SHR_F32(rs, 0x114);
            rs += DPP_SHR_F32(rs, 0x118);
            if ((lane & 15) == 15) atomicAdd(&rowsum[grow], rs);

            if (is_cross) {
                // top-2 merge over the 16-lane row via DPP tree -> lane 15
                TOP2_DPP_STEP(t1, t2, 0x111);
                TOP2_DPP_STEP(t1, t2, 0x112);
                TOP2_DPP_STEP(t1, t2, 0x114);
                TOP2_DPP_STEP(t1, t2, 0x118);
                if ((lane & 15) == 15)
                    partial[((size_t)grow << 6) + (bx - 32) * 2 + wc] = make_uint2(t1, t2);
            }
        }
    }

    // ---- col-side finalize (crosses 16-lane rows: keep shfl) ----
    if (off_diag) {
#pragma unroll
        for (int n = 0; n < 4; n++) {
            float c = cs0[n] + cs1[n];
            c += __shfl_xor(c, 16);
            c += __shfl_xor(c, 32);
            // merge the two top-2 halves
            uint32_t a1 = umax32(s1a[n], s1b[n]);
            uint32_t a2 = umax32(umin32(s1a[n], s1b[n]), umax32(s2a[n], s2b[n]));
            if (is_cross) {
#pragma unroll
                for (int o = 16; o < 64; o <<= 1) {
                    uint32_t o1 = __shfl_xor(a1, o);
                    uint32_t o2 = __shfl_xor(a2, o);
                    uint32_t nt2 = umax32(umin32(a1, o1), umax32(a2, o2));
                    a1 = umax32(a1, o1);
                    a2 = nt2;
                }
            }
            if (lane < 16) {
                int gcol = bcol + wc * 64 + n * 16 + lane;
                atomicAdd(&rowsum[gcol], c);
                if (is_cross)
                    partial[((size_t)gcol << 6) + by * 2 + wr] = make_uint2(a1, a2);
            }
        }
    }
}

// ------- Kernel 2: per-row top-10 + per-row loss (R12 structure) -------
// 2048 blocks x 4 rows, one row per wave; writes contrib[] (no atomics).
__global__ __launch_bounds__(256) void topk_loss_kernel(const uint2* __restrict__ partial,
                                                        const float* __restrict__ pos_sim,
                                                        const float* __restrict__ rowsum,
                                                        float* __restrict__ contrib)
{
    int i    = blockIdx.x * 4 + (threadIdx.x >> 6);
    int lane = threadIdx.x & 63;

    uint2 p = partial[((size_t)i << 6) + lane];
    uint32_t t1 = p.x, t2 = p.y;

    int posidx = i & (HALF_N - 1);
    float S10 = 0.f; int posflag = 0;
#pragma unroll
    for (int tc = 0; tc < 10; tc++) {
        uint32_t b = umax32(t1, t2);
#pragma unroll
        for (int o = 32; o; o >>= 1)
            b = umax32(b, __shfl_xor(b, o));
        bool w1 = (b == t1);
        bool w2 = (b == t2);
        t1 = w1 ? t2 : t1;
        t2 = (w1 | w2) ? 0u : t2;

        int idx = 4095 - (int)(b & 0xFFFFu);
        S10 += decode_key(b >> 16);
        posflag |= (idx == posidx) ? 1 : 0;
    }

    if (lane == 0) {
        float ps  = pos_sim[i];
        float lse = logf(rowsum[i]);
        float L   = 1.0f + 0.75f * (10 - posflag);
        float sll = INV_TAU * (ps + 0.75f * (S10 - posflag * ps));
        contrib[i] = L * lse - sll;
    }
}

// ------- Kernel 3: deterministic final reduce --------------------------
__global__ __launch_bounds__(256) void reduce_kernel(const float* __restrict__ contrib,
                                                     float* __restrict__ out)
{
    int t = threadIdx.x;
    float s = 0.f;
    for (int j = t; j < N_TOTAL; j += 256) s += contrib[j];
#pragma unroll
    for (int o = 1; o < 64; o <<= 1) s += __shfl_xor(s, o);
    __shared__ float wsum[4];
    if ((t & 63) == 0) wsum[t >> 6] = s;
    __syncthreads();
    if (t == 0) out[0] = (wsum[0] + wsum[1] + wsum[2] + wsum[3]) * (1.0f / N_TOTAL);
}

extern "C" void kernel_launch(void* const* d_in, const int* in_sizes, int n_in,
                              void* d_out, int out_size, void* d_ws, size_t ws_size,
                              hipStream_t stream)
{
    const float* z1 = (const float*)d_in[0];
    const float* z2 = (const float*)d_in[1];
    float* out = (float*)d_out;

    char* ws = (char*)d_ws;
    char*   zq      = ws;                              //  4 MB   8192x512 int8
    float*  rowsum  = (float*)(ws + 4194304);          // 32 KB
    float*  pos_sim = (float*)(ws + 4227072);          // 32 KB
    float*  inv_e   = (float*)(ws + 4259840);          // 32 KB
    uint2*  partial = (uint2*)(ws + 4292608);          //  4 MB   8192x64 uint2
    float*  contrib = (float*)(ws + 8486912);          // 32 KB

    norm_kernel<<<N_TOTAL / 4, 256, 0, stream>>>(z1, z2, zq, inv_e, rowsum);
    gemm_kernel<<<2080, 256, 0, stream>>>(zq, inv_e, rowsum, partial, pos_sim);
    topk_loss_kernel<<<N_TOTAL / 4, 256, 0, stream>>>(partial, pos_sim, rowsum, contrib);
    reduce_kernel<<<1, 256, 0, stream>>>(contrib, out);
}

// Round 19
// 81.778 us; speedup vs baseline: 1.6952x; 1.0425x over previous
//
#include <hip/hip_runtime.h>
#include <hip/hip_bf16.h>
#include <stdint.h>

#define N_TOTAL 8192
#define HALF_N  4096
#define DIM     512
#define INV_TAU (1.0f/0.07f)
// exp2 fold: e = exp2(sim * INV_TAU * log2e); SCALE^2 = INV_TAU*log2e
#define EXP2_SCALE  4.5398160046388386f     /* sqrt(20.60992915555662) */
#define SIM_FROM_VE 0.0485203026391962f     /* 0.07 * ln2 */

typedef __attribute__((ext_vector_type(4))) int   i32x4;

#define AS1 __attribute__((address_space(1)))
#define AS3 __attribute__((address_space(3)))

__device__ __forceinline__ uint32_t umax32(uint32_t a, uint32_t b) { return a > b ? a : b; }
__device__ __forceinline__ uint32_t umin32(uint32_t a, uint32_t b) { return a < b ? a : b; }

// DPP row_shr step: lane l reads lane l-N within its 16-lane row;
// out-of-row reads 0 (bound_ctrl=1) — identity for f32-add and u32-max.
#define DPP_SHR_F32(x, ctrl) \
    __int_as_float(__builtin_amdgcn_update_dpp(0, __float_as_int(x), (ctrl), 0xf, 0xf, true))
#define DPP_SHR_U32(x, ctrl) \
    ((uint32_t)__builtin_amdgcn_update_dpp(0, (int)(x), (ctrl), 0xf, 0xf, true))

// one top-2 merge step with literal ctrl (DPP ctrl must be parse-time const)
#define TOP2_DPP_STEP(t1, t2, ctrl) do {                                           \
    uint32_t o1_ = DPP_SHR_U32(t1, ctrl);                                          \
    uint32_t o2_ = DPP_SHR_U32(t2, ctrl);                                          \
    uint32_t mn_ = umin32(t1, o1_);                                                \
    t1 = umax32(t1, o1_);                                                          \
    o2_ = umax32(t2, o2_);                                                         \
    t2 = umax32(mn_, o2_);                                                         \
} while (0)

__device__ __forceinline__ float decode_key(uint32_t key)
{
    ushort h = (key & 0x8000u) ? (ushort)(key ^ 0x8000u) : (ushort)(key ^ 0xFFFFu);
    return (float)(*(_Float16*)&h);
}

// ------- Kernel 0: normalize -> int8 quantize; inv_e = EXP2_SCALE/|q|;
//         zero rowsum --------------------------------------------------
__global__ __launch_bounds__(256) void norm_kernel(const float* __restrict__ z1,
                                                   const float* __restrict__ z2,
                                                   char* __restrict__ zq,
                                                   float* __restrict__ inv_e,
                                                   float* __restrict__ rowsum)
{
    if (threadIdx.x < 4) rowsum[blockIdx.x * 4 + threadIdx.x] = 0.f;

    int row  = blockIdx.x * 4 + (threadIdx.x >> 6);
    int lane = threadIdx.x & 63;
    const float* src = (row < HALF_N) ? (z1 + (size_t)row * DIM)
                                      : (z2 + (size_t)(row - HALF_N) * DIM);
    const float4* p = (const float4*)src;
    float4 a = p[lane * 2];
    float4 b = p[lane * 2 + 1];
    float ss = a.x*a.x + a.y*a.y + a.z*a.z + a.w*a.w
             + b.x*b.x + b.y*b.y + b.z*b.z + b.w*b.w;
#pragma unroll
    for (int o = 1; o < 64; o <<= 1) ss += __shfl_xor(ss, o);
    float sc = 127.0f / fmaxf(sqrtf(ss), 1e-12f);

    float v[8] = {a.x*sc, a.y*sc, a.z*sc, a.w*sc, b.x*sc, b.y*sc, b.z*sc, b.w*sc};
    char c8[8];
    int qq = 0;
#pragma unroll
    for (int j = 0; j < 8; j++) {
        int qi = (int)rintf(v[j]);
        qq += qi * qi;
        c8[j] = (char)qi;
    }
#pragma unroll
    for (int o = 1; o < 64; o <<= 1) qq += __shfl_xor(qq, o);
    if (lane == 0) inv_e[row] = EXP2_SCALE / sqrtf(fmaxf((float)qq, 1.0f));

    *(uint2*)(zq + (size_t)row * DIM + lane * 8) = *(const uint2*)c8;
}

// ------- Kernel 1: upper-triangle 128x128 int8 MFMA GEMM ---------------
// R19: prefetch the wave's 16 row-norms (inv_e) as 4x float4 BEFORE the
// epilogue loop — kills the per-(m,r) dependent global load that fed the
// cvt/mul/exp2 chain (16 x ~200cyc serial L2 latency at only 2.4
// waves/SIMD of TLP). All other code identical to R18.
__global__ __launch_bounds__(256, 4) void gemm_kernel(const char* __restrict__ zq,
                                                      const float* __restrict__ inv_e,
                                                      float* __restrict__ rowsum,
                                                      uint2* __restrict__ partial,
                                                      float* __restrict__ pos_sim)
{
    // XCD-aware swizzle: 2080 = 8 * 260, bijective
    int orig = blockIdx.x;
    int bid  = (orig & 7) * 260 + (orig >> 3);

    // triangular decode: bid -> (by, bx), bx >= by
    int by = (int)(64.5f - sqrtf(4160.25f - 2.0f * (float)bid));
    int off = 64 * by - (by * (by - 1)) / 2;
    if (off > bid) { --by; off = 64 * by - (by * (by - 1)) / 2; }
    else {
        int offn = 64 * (by + 1) - ((by + 1) * by) / 2;
        if (offn <= bid) { ++by; off = offn; }
    }
    int bx = by + (bid - off);

    const int brow = by * 128;
    const int bcol = bx * 128;

    __shared__ char As[2][128 * 64];   // 8 KB per buffer
    __shared__ char Bs[2][128 * 64];   // 32 KB total

    const int t    = threadIdx.x;
    const int w    = t >> 6;
    const int lane = t & 63;
    const int wr   = w >> 1, wc = w & 1;       // 2x2 waves of 64x64

    i32x4 acc[4][4] = {};

    const int c0 = t, c1 = 256 + t;
    const int r0 = c0 >> 2, r1 = c1 >> 2;
    const int q0 = (c0 & 3) ^ ((r0 >> 1) & 3);
    const int q1 = (c1 & 3) ^ ((r1 >> 1) & 3);
    const size_t gaA0 = (size_t)(brow + r0) * DIM + q0 * 16;
    const size_t gaA1 = (size_t)(brow + r1) * DIM + q1 * 16;
    const size_t gaB0 = (size_t)(bcol + r0) * DIM + q0 * 16;
    const size_t gaB1 = (size_t)(bcol + r1) * DIM + q1 * 16;
    const int l0 = (w * 64) * 16;
    const int l1 = (256 + w * 64) * 16;

#define STAGE(buf, ko) do {                                                        \
    __builtin_amdgcn_global_load_lds((const AS1 uint32_t*)(zq + gaA0 + (ko)),      \
        (AS3 uint32_t*)((char*)As[buf] + l0), 16, 0, 0);                           \
    __builtin_amdgcn_global_load_lds((const AS1 uint32_t*)(zq + gaA1 + (ko)),      \
        (AS3 uint32_t*)((char*)As[buf] + l1), 16, 0, 0);                           \
    __builtin_amdgcn_global_load_lds((const AS1 uint32_t*)(zq + gaB0 + (ko)),      \
        (AS3 uint32_t*)((char*)Bs[buf] + l0), 16, 0, 0);                           \
    __builtin_amdgcn_global_load_lds((const AS1 uint32_t*)(zq + gaB1 + (ko)),      \
        (AS3 uint32_t*)((char*)Bs[buf] + l1), 16, 0, 0);                           \
} while (0)

    STAGE(0, 0);
    __syncthreads();

    int cur = 0;
    for (int kt = 0; kt < DIM / 64; ++kt) {
        if (kt + 1 < DIM / 64) STAGE(cur ^ 1, (kt + 1) * 64);

        i32x4 av[4], bv[4];
#pragma unroll
        for (int m = 0; m < 4; m++) {
            int ro = wr * 64 + m * 16 + (lane & 15);
            int s  = (lane >> 4) ^ ((ro >> 1) & 3);
            av[m] = *(const i32x4*)(As[cur] + ro * 64 + s * 16);
        }
#pragma unroll
        for (int n = 0; n < 4; n++) {
            int ro = wc * 64 + n * 16 + (lane & 15);
            int s  = (lane >> 4) ^ ((ro >> 1) & 3);
            bv[n] = *(const i32x4*)(Bs[cur] + ro * 64 + s * 16);
        }
#pragma unroll
        for (int m = 0; m < 4; m++)
#pragma unroll
            for (int n = 0; n < 4; n++)
                acc[m][n] = __builtin_amdgcn_mfma_i32_16x16x64_i8(av[m], bv[n], acc[m][n], 0, 0, 0);

        __syncthreads();
        cur ^= 1;
    }
#undef STAGE

    const bool is_cross = (brow < HALF_N) && (bcol >= HALF_N);
    const bool off_diag = (bx != by);

    // prefetch column norms (coalesced) and THIS WAVE'S 16 row norms
    // (4x float4, issued together — no dependent load inside the loop)
    float invc[4];
#pragma unroll
    for (int n = 0; n < 4; n++)
        invc[n] = inv_e[bcol + wc * 64 + n * 16 + (lane & 15)];

    float invr_[4][4];
#pragma unroll
    for (int m = 0; m < 4; m++) {
        float4 v4 = *(const float4*)&inv_e[brow + wr * 64 + m * 16 + ((lane >> 4) << 2)];
        invr_[m][0] = v4.x; invr_[m][1] = v4.y; invr_[m][2] = v4.z; invr_[m][3] = v4.w;
    }

    // 2-way split accumulators (halve the loop-carried dep chains)
    float    cs0[4] = {0,0,0,0}, cs1[4] = {0,0,0,0};
    uint32_t s1a[4] = {0,0,0,0}, s2a[4] = {0,0,0,0};
    uint32_t s1b[4] = {0,0,0,0}, s2b[4] = {0,0,0,0};

    // ---- single fused epilogue pass ----
#pragma unroll
    for (int m = 0; m < 4; m++) {
#pragma unroll
        for (int r = 0; r < 4; r++) {
            int grow = brow + wr * 64 + m * 16 + ((lane >> 4) << 2) + r;
            float invr = invr_[m][r];
            float rs = 0.f;
            uint32_t t1 = 0u, t2 = 0u;
#pragma unroll
            for (int n = 0; n < 4; n++) {
                int gcol = bcol + wc * 64 + n * 16 + (lane & 15);
                float ve = (float)acc[m][n][r] * (invr * invc[n]);   // sim*INV_TAU*log2e
                float e  = (grow == gcol) ? 0.f : __builtin_exp2f(ve);
                rs += e;
                if (m < 2) cs0[n] += e; else cs1[n] += e;
                if (is_cross) {
                    float v = ve * SIM_FROM_VE;                      // raw sim
                    int cidx = gcol - HALF_N;
                    ushort h;
                    *(_Float16*)&h = (_Float16)v;
                    uint32_t key = ((uint32_t)(ushort)(h ^ (ushort)((ushort)((short)h >> 15) | 0x8000))) << 16;
                    uint32_t xr = key | (uint32_t)(4095 - cidx);
                    uint32_t mn = umin32(t1, xr);
                    t1 = umax32(t1, xr);
                    t2 = umax32(t2, mn);
                    uint32_t xc = key | (uint32_t)(4095 - grow);
                    if (m < 2) {
                        mn = umin32(s1a[n], xc); s1a[n] = umax32(s1a[n], xc); s2a[n] = umax32(s2a[n], mn);
                    } else {
                        mn = umin32(s1b[n], xc); s1b[n] = umax32(s1b[n], xc); s2b[n] = umax32(s2b[n], mn);
                    }
                    if (cidx == grow) { pos_sim[grow] = v; pos_sim[gcol] = v; }
                }
            }
            // rs sum over the 16-lane row via DPP row_shr tree -> lane 15
            rs += DPP_SHR_F32(rs, 0x111);
            rs += DPP_SHR_F32(rs, 0x112);
            rs += DPP_SHR_F32(rs, 0x114);
            rs += DPP_SHR_F32(rs, 0x118);
            if ((lane & 15) == 15) atomicAdd(&rowsum[grow], rs);

            if (is_cross) {
                // top-2 merge over the 16-lane row via DPP tree -> lane 15
                TOP2_DPP_STEP(t1, t2, 0x111);
                TOP2_DPP_STEP(t1, t2, 0x112);
                TOP2_DPP_STEP(t1, t2, 0x114);
                TOP2_DPP_STEP(t1, t2, 0x118);
                if ((lane & 15) == 15)
                    partial[((size_t)grow << 6) + (bx - 32) * 2 + wc] = make_uint2(t1, t2);
            }
        }
    }

    // ---- col-side finalize (crosses 16-lane rows: keep shfl) ----
    if (off_diag) {
#pragma unroll
        for (int n = 0; n < 4; n++) {
            float c = cs0[n] + cs1[n];
            c += __shfl_xor(c, 16);
            c += __shfl_xor(c, 32);
            // merge the two top-2 halves
            uint32_t a1 = umax32(s1a[n], s1b[n]);
            uint32_t a2 = umax32(umin32(s1a[n], s1b[n]), umax32(s2a[n], s2b[n]));
            if (is_cross) {
#pragma unroll
                for (int o = 16; o < 64; o <<= 1) {
                    uint32_t o1 = __shfl_xor(a1, o);
                    uint32_t o2 = __shfl_xor(a2, o);
                    uint32_t nt2 = umax32(umin32(a1, o1), umax32(a2, o2));
                    a1 = umax32(a1, o1);
                    a2 = nt2;
                }
            }
            if (lane < 16) {
                int gcol = bcol + wc * 64 + n * 16 + lane;
                atomicAdd(&rowsum[gcol], c);
                if (is_cross)
                    partial[((size_t)gcol << 6) + by * 2 + wr] = make_uint2(a1, a2);
            }
        }
    }
}

// ------- Kernel 2: per-row top-10 + per-row loss (R12 structure) -------
// 2048 blocks x 4 rows, one row per wave; writes contrib[] (no atomics).
__global__ __launch_bounds__(256) void topk_loss_kernel(const uint2* __restrict__ partial,
                                                        const float* __restrict__ pos_sim,
                                                        const float* __restrict__ rowsum,
                                                        float* __restrict__ contrib)
{
    int i    = blockIdx.x * 4 + (threadIdx.x >> 6);
    int lane = threadIdx.x & 63;

    uint2 p = partial[((size_t)i << 6) + lane];
    uint32_t t1 = p.x, t2 = p.y;

    int posidx = i & (HALF_N - 1);
    float S10 = 0.f; int posflag = 0;
#pragma unroll
    for (int tc = 0; tc < 10; tc++) {
        uint32_t b = umax32(t1, t2);
#pragma unroll
        for (int o = 32; o; o >>= 1)
            b = umax32(b, __shfl_xor(b, o));
        bool w1 = (b == t1);
        bool w2 = (b == t2);
        t1 = w1 ? t2 : t1;
        t2 = (w1 | w2) ? 0u : t2;

        int idx = 4095 - (int)(b & 0xFFFFu);
        S10 += decode_key(b >> 16);
        posflag |= (idx == posidx) ? 1 : 0;
    }

    if (lane == 0) {
        float ps  = pos_sim[i];
        float lse = logf(rowsum[i]);
        float L   = 1.0f + 0.75f * (10 - posflag);
        float sll = INV_TAU * (ps + 0.75f * (S10 - posflag * ps));
        contrib[i] = L * lse - sll;
    }
}

// ------- Kernel 3: deterministic final reduce --------------------------
__global__ __launch_bounds__(256) void reduce_kernel(const float* __restrict__ contrib,
                                                     float* __restrict__ out)
{
    int t = threadIdx.x;
    float s = 0.f;
    for (int j = t; j < N_TOTAL; j += 256) s += contrib[j];
#pragma unroll
    for (int o = 1; o < 64; o <<= 1) s += __shfl_xor(s, o);
    __shared__ float wsum[4];
    if ((t & 63) == 0) wsum[t >> 6] = s;
    __syncthreads();
    if (t == 0) out[0] = (wsum[0] + wsum[1] + wsum[2] + wsum[3]) * (1.0f / N_TOTAL);
}

extern "C" void kernel_launch(void* const* d_in, const int* in_sizes, int n_in,
                              void* d_out, int out_size, void* d_ws, size_t ws_size,
                              hipStream_t stream)
{
    const float* z1 = (const float*)d_in[0];
    const float* z2 = (const float*)d_in[1];
    float* out = (float*)d_out;

    char* ws = (char*)d_ws;
    char*   zq      = ws;                              //  4 MB   8192x512 int8
    float*  rowsum  = (float*)(ws + 4194304);          // 32 KB
    float*  pos_sim = (float*)(ws + 4227072);          // 32 KB
    float*  inv_e   = (float*)(ws + 4259840);          // 32 KB
    uint2*  partial = (uint2*)(ws + 4292608);          //  4 MB   8192x64 uint2
    float*  contrib = (float*)(ws + 8486912);          // 32 KB

    norm_kernel<<<N_TOTAL / 4, 256, 0, stream>>>(z1, z2, zq, inv_e, rowsum);
    gemm_kernel<<<2080, 256, 0, stream>>>(zq, inv_e, rowsum, partial, pos_sim);
    topk_loss_kernel<<<N_TOTAL / 4, 256, 0, stream>>>(partial, pos_sim, rowsum, contrib);
    reduce_kernel<<<1, 256, 0, stream>>>(contrib, out);
}